// Round 5
// baseline (149.383 us; speedup 1.0000x reference)
//
#include <hip/hip_runtime.h>

typedef __attribute__((ext_vector_type(8))) short s16x8;
typedef __attribute__((ext_vector_type(4))) float f32x4;

#define THREADS 704
#define WAVES 11
#define TROWS 32
#define RPB (WAVES * TROWS)   // 352 rows per block-tile

__device__ __forceinline__ short f2bf(float f) {
    unsigned u = __float_as_uint(f);
    u += 0x7fffu + ((u >> 16) & 1u);
    return (short)(u >> 16);
}

__device__ __forceinline__ unsigned cvt_pk(float lo, float hi) {
    unsigned r;
    asm("v_cvt_pk_bf16_f32 %0, %1, %2" : "=v"(r) : "v"(lo), "v"(hi));
    return r;
}

// swizzled ushort index into a [rows][128] bf16 tile
__device__ __forceinline__ int swz(int row, int col) {
    return (row * 128 + col) ^ ((row & 7) << 3);
}

template <int S>
__device__ __forceinline__ float dpp_ror(float v) {
    int x = __builtin_amdgcn_update_dpp(0, __float_as_int(v), 0x120 | S, 0xf, 0xf, false);
    return __int_as_float(x);
}

__device__ __forceinline__ float red16(float v) {
    v += dpp_ror<1>(v);
    v += dpp_ror<2>(v);
    v += dpp_ror<4>(v);
    v += dpp_ror<8>(v);
    return v;
}

// pack 8 f32 -> bf16x8 A-fragment
__device__ __forceinline__ s16x8 pack8(float4 a, float4 b) {
    union { unsigned u[4]; s16x8 v; } z;
    z.u[0] = cvt_pk(a.x, a.y); z.u[1] = cvt_pk(a.z, a.w);
    z.u[2] = cvt_pk(b.x, b.y); z.u[3] = cvt_pk(b.z, b.w);
    return z.v;
}

__launch_bounds__(THREADS, 3)
__global__ void edgeface_kernel(
    const float* __restrict__ topo, const int* __restrict__ esid,
    const float* __restrict__ W1, const float* __restrict__ b1,
    const float* __restrict__ W2, const float* __restrict__ b2,
    const float* __restrict__ W3, const float* __restrict__ b3,
    float* __restrict__ out, int nRows, int kg)
{
    __shared__ __align__(16) short sW1[128 * 128];          // 32 KB
    __shared__ __align__(16) short sW2[128 * 128];          // 32 KB
    __shared__ __align__(16) short sH[WAVES * TROWS * 128]; // 88 KB (H1 per wave)

    const int tid = threadIdx.x;

    for (int idx = tid; idx < 128 * 128; idx += THREADS) {
        int kk = idx >> 7, n = idx & 127;
        int d = swz(n, kk);
        sW1[d] = f2bf(W1[idx]);
        sW2[d] = f2bf(W2[idx]);
    }
    __syncthreads();

    const int w = tid >> 6, lane = tid & 63;
    short* ht = sH + w * (TROWS * 128);
    const int r = lane & 15;   // A-row within 16 / D-col
    const int g = lane >> 4;   // k-quarter / D-row-group

    float rb1[8], rb2[8], w3d[8];
    #pragma unroll
    for (int t = 0; t < 8; ++t) {
        int c = t * 16 + r;
        rb1[t] = b1[c];
        rb2[t] = b2[c];
        w3d[t] = W3[c * 2 + 1] - W3[c * 2 + 0];
    }
    const float b3d = b3[1] - b3[0];

    const int G = gridDim.x;
    const int nTiles = (nRows + RPB - 1) / RPB;

    // esid for this lane's two gather rows (r and 16+r) of the first tile
    int e0a, e1a, e2a, e0b, e1b, e2b;
    {
        int base = blockIdx.x * RPB + w * TROWS;
        int na = min(base + r, nRows - 1) / 3;
        int nb = min(base + 16 + r, nRows - 1) / 3;
        e0a = esid[na * 3 + 0]; e1a = esid[na * 3 + 1]; e2a = esid[na * 3 + 2];
        e0b = esid[nb * 3 + 0]; e1b = esid[nb * 3 + 1]; e2b = esid[nb * 3 + 2];
    }

    for (int tI = blockIdx.x; tI < nTiles; tI += G) {
        const int base = tI * RPB + w * TROWS;

        // ---- direct-to-A gather: lane (r,g) loads its own fragment chunks ----
        int Ra = min(base + r, nRows - 1);
        int fa = Ra - 3 * (Ra / 3);
        long ea = (((long)e0a * kg + e1a) * kg + e2a) * 64;
        long na = ((((long)((fa == 0) ? max(e0a - 1, 0) : e0a)) * kg
                  + ((fa == 1) ? max(e1a - 1, 0) : e1a)) * kg
                  + ((fa == 2) ? max(e2a - 1, 0) : e2a)) * 64;
        int Rb = min(base + 16 + r, nRows - 1);
        int fb = Rb - 3 * (Rb / 3);
        long eb = (((long)e0b * kg + e1b) * kg + e2b) * 64;
        long nb = ((((long)((fb == 0) ? max(e0b - 1, 0) : e0b)) * kg
                  + ((fb == 1) ? max(e1b - 1, 0) : e1b)) * kg
                  + ((fb == 2) ? max(e2b - 1, 0) : e2b)) * 64;

        const float4* pea = (const float4*)(topo + ea);
        const float4* pna = (const float4*)(topo + na);
        const float4* peb = (const float4*)(topo + eb);
        const float4* pnb = (const float4*)(topo + nb);

        float4 x0 = pea[2*g+0], x1 = pea[2*g+1], x2 = pea[8+2*g+0], x3 = pea[8+2*g+1];
        float4 x4 = pna[2*g+0], x5 = pna[2*g+1], x6 = pna[8+2*g+0], x7 = pna[8+2*g+1];
        float4 y0 = peb[2*g+0], y1 = peb[2*g+1], y2 = peb[8+2*g+0], y3 = peb[8+2*g+1];
        float4 y4 = pnb[2*g+0], y5 = pnb[2*g+1], y6 = pnb[8+2*g+0], y7 = pnb[8+2*g+1];

        // preload esid for the next tile while gathers are in flight
        {
            int nbase = (tI + G) * RPB + w * TROWS;
            int nna = min(nbase + r, nRows - 1) / 3;
            int nnb = min(nbase + 16 + r, nRows - 1) / 3;
            e0a = esid[nna * 3 + 0]; e1a = esid[nna * 3 + 1]; e2a = esid[nna * 3 + 2];
            e0b = esid[nnb * 3 + 0]; e1b = esid[nnb * 3 + 1]; e2b = esid[nnb * 3 + 2];
        }

        s16x8 a0[4], a1[4];
        a0[0] = pack8(x0, x1); a0[1] = pack8(x2, x3);
        a0[2] = pack8(x4, x5); a0[3] = pack8(x6, x7);
        a1[0] = pack8(y0, y1); a1[1] = pack8(y2, y3);
        a1[2] = pack8(y4, y5); a1[3] = pack8(y6, y7);

        // ---- layer 1: eager per-t epilogue (acc lives only within t) ----
        #pragma unroll
        for (int t = 0; t < 8; ++t) {
            f32x4 c0 = {0.f, 0.f, 0.f, 0.f}, c1 = {0.f, 0.f, 0.f, 0.f};
            #pragma unroll
            for (int ks = 0; ks < 4; ++ks) {
                s16x8 bf = *(const s16x8*)(sW1 + swz(t * 16 + r, ks * 32 + g * 8));
                c0 = __builtin_amdgcn_mfma_f32_16x16x32_bf16(a0[ks], bf, c0, 0, 0, 0);
                c1 = __builtin_amdgcn_mfma_f32_16x16x32_bf16(a1[ks], bf, c1, 0, 0, 0);
            }
            int col = t * 16 + r;
            {
                unsigned pA = cvt_pk(fmaxf(c0[0] + rb1[t], 0.f), fmaxf(c0[1] + rb1[t], 0.f));
                unsigned pB = cvt_pk(fmaxf(c0[2] + rb1[t], 0.f), fmaxf(c0[3] + rb1[t], 0.f));
                ht[swz(g * 4 + 0, col)] = (short)pA;
                ht[swz(g * 4 + 1, col)] = (short)(pA >> 16);
                ht[swz(g * 4 + 2, col)] = (short)pB;
                ht[swz(g * 4 + 3, col)] = (short)(pB >> 16);
            }
            {
                unsigned pA = cvt_pk(fmaxf(c1[0] + rb1[t], 0.f), fmaxf(c1[1] + rb1[t], 0.f));
                unsigned pB = cvt_pk(fmaxf(c1[2] + rb1[t], 0.f), fmaxf(c1[3] + rb1[t], 0.f));
                ht[swz(16 + g * 4 + 0, col)] = (short)pA;
                ht[swz(16 + g * 4 + 1, col)] = (short)(pA >> 16);
                ht[swz(16 + g * 4 + 2, col)] = (short)pB;
                ht[swz(16 + g * 4 + 3, col)] = (short)(pB >> 16);
            }
        }

        // ---- layer 2 + fused layer-3 logit-diff ----
        #pragma unroll
        for (int ks = 0; ks < 4; ++ks) {
            a0[ks] = *(const s16x8*)(ht + swz(r,      ks * 32 + g * 8));
            a1[ks] = *(const s16x8*)(ht + swz(16 + r, ks * 32 + g * 8));
        }
        float pd0[4] = {0.f, 0.f, 0.f, 0.f}, pd1[4] = {0.f, 0.f, 0.f, 0.f};
        #pragma unroll
        for (int t = 0; t < 8; ++t) {
            f32x4 c0 = {0.f, 0.f, 0.f, 0.f}, c1 = {0.f, 0.f, 0.f, 0.f};
            #pragma unroll
            for (int ks = 0; ks < 4; ++ks) {
                s16x8 bf = *(const s16x8*)(sW2 + swz(t * 16 + r, ks * 32 + g * 8));
                c0 = __builtin_amdgcn_mfma_f32_16x16x32_bf16(a0[ks], bf, c0, 0, 0, 0);
                c1 = __builtin_amdgcn_mfma_f32_16x16x32_bf16(a1[ks], bf, c1, 0, 0, 0);
            }
            #pragma unroll
            for (int i = 0; i < 4; ++i) {
                float h0 = fmaxf(c0[i] + rb2[t], 0.f);
                float h1 = fmaxf(c1[i] + rb2[t], 0.f);
                pd0[i] = fmaf(h0, w3d[t], pd0[i]);
                pd1[i] = fmaf(h1, w3d[t], pd1[i]);
            }
        }
        #pragma unroll
        for (int i = 0; i < 4; ++i) {
            pd0[i] = red16(pd0[i]);
            pd1[i] = red16(pd1[i]);
        }

        // ---- softmax + store (lane r = i*2 + o, r<8) ----
        if (r < 8) {
            int i = r >> 1, o = r & 1;
            float d0 = ((i == 0) ? pd0[0] : (i == 1) ? pd0[1] : (i == 2) ? pd0[2] : pd0[3]) + b3d;
            float d1 = ((i == 0) ? pd1[0] : (i == 1) ? pd1[1] : (i == 2) ? pd1[2] : pd1[3]) + b3d;
            float p0 = 1.f / (1.f + __expf(o ? -d0 : d0));
            float p1 = 1.f / (1.f + __expf(o ? -d1 : d1));
            int R0 = base + g * 4 + i;
            int R1 = base + 16 + g * 4 + i;
            if (R0 < nRows) {
                int n = R0 / 3, ff = R0 - 3 * n;
                out[n * 6 + o * 3 + ff] = p0;
            }
            if (R1 < nRows) {
                int n = R1 / 3, ff = R1 - 3 * n;
                out[n * 6 + o * 3 + ff] = p1;
            }
        }
    }
}

extern "C" void kernel_launch(void* const* d_in, const int* in_sizes, int n_in,
                              void* d_out, int out_size, void* d_ws, size_t ws_size,
                              hipStream_t stream) {
    const float* topo = (const float*)d_in[0];
    const int*   esid = (const int*)d_in[1];
    const float* W1 = (const float*)d_in[2];
    const float* b1 = (const float*)d_in[3];
    const float* W2 = (const float*)d_in[4];
    const float* b2 = (const float*)d_in[5];
    const float* W3 = (const float*)d_in[6];
    const float* b3 = (const float*)d_in[7];
    float* out = (float*)d_out;

    int nRows = in_sizes[1];
    int H = in_sizes[3];
    int F = (in_sizes[2] / H) / 2;
    long vol = (long)in_sizes[0] / F;
    int kg = 1;
    while ((long)(kg + 1) * (kg + 1) * (kg + 1) <= vol) ++kg;

    if (nRows <= 0) return;
    edgeface_kernel<<<dim3(256), dim3(THREADS), 0, stream>>>(
        topo, esid, W1, b1, W2, b2, W3, b3, out, nRows, kg);
}

// Round 6
// 87.377 us; speedup vs baseline: 1.7096x; 1.7096x over previous
//
#include <hip/hip_runtime.h>

typedef __attribute__((ext_vector_type(8))) short s16x8;
typedef __attribute__((ext_vector_type(16))) float f32x16;

#define THREADS 704
#define WAVES 11
#define TROWS 32
#define RPB (WAVES * TROWS)   // 352 rows per block-tile

__device__ __forceinline__ short f2bf(float f) {
    unsigned u = __float_as_uint(f);
    u += 0x7fffu + ((u >> 16) & 1u);
    return (short)(u >> 16);
}

__device__ __forceinline__ unsigned cvt_pk(float lo, float hi) {
    unsigned r;
    asm("v_cvt_pk_bf16_f32 %0, %1, %2" : "=v"(r) : "v"(lo), "v"(hi));
    return r;
}

// swizzled ushort index into a [rows][128] bf16 tile; 16-granule XOR period
// (32 distinct rows spread over 16 16B-slots; col must be multiple of 8 for b128)
__device__ __forceinline__ int swz(int row, int col) {
    return row * 128 + ((((col >> 3) ^ (row & 15)) << 3) | (col & 7));
}

template <int S>
__device__ __forceinline__ float dpp_ror(float v) {
    int x = __builtin_amdgcn_update_dpp(0, __float_as_int(v), 0x120 | S, 0xf, 0xf, false);
    return __int_as_float(x);
}

// sum within each aligned 16-lane group (VALU-only)
__device__ __forceinline__ float red16(float v) {
    v += dpp_ror<1>(v);
    v += dpp_ror<2>(v);
    v += dpp_ror<4>(v);
    v += dpp_ror<8>(v);
    return v;
}

// write 8 f32 as bf16x8 to swizzled tile
__device__ __forceinline__ void store8(short* tile, int row, int col, float4 a, float4 b) {
    union { unsigned u[4]; s16x8 v; } z;
    z.u[0] = cvt_pk(a.x, a.y); z.u[1] = cvt_pk(a.z, a.w);
    z.u[2] = cvt_pk(b.x, b.y); z.u[3] = cvt_pk(b.z, b.w);
    *(s16x8*)(tile + swz(row, col)) = z.v;
}

__launch_bounds__(THREADS, 3)
__global__ void edgeface_kernel(
    const float* __restrict__ topo, const int* __restrict__ esid,
    const float* __restrict__ W1, const float* __restrict__ b1,
    const float* __restrict__ W2, const float* __restrict__ b2,
    const float* __restrict__ W3, const float* __restrict__ b3,
    float* __restrict__ out, int nRows, int kg)
{
    __shared__ __align__(16) short sW1[128 * 128];          // 32 KB, Wt[n][k]
    __shared__ __align__(16) short sW2[128 * 128];          // 32 KB
    __shared__ __align__(16) short sT[WAVES * TROWS * 128]; // 88 KB X/H per wave

    const int tid = threadIdx.x;

    for (int idx = tid; idx < 128 * 128; idx += THREADS) {
        int kk = idx >> 7, n = idx & 127;
        int d = swz(n, kk);
        sW1[d] = f2bf(W1[idx]);
        sW2[d] = f2bf(W2[idx]);
    }
    __syncthreads();

    const int w = tid >> 6, lane = tid & 63;
    short* tile = sT + w * (TROWS * 128);
    const int c31 = lane & 31;   // A-row / C-col within 32
    const int h   = lane >> 5;   // k-half / C-row offset

    // per-lane constants: this lane's output-column slice per n-tile
    float rb1[4], rb2[4], w3d[4];
    #pragma unroll
    for (int n = 0; n < 4; ++n) {
        int col = n * 32 + c31;
        rb1[n] = b1[col];
        rb2[n] = b2[col];
        w3d[n] = W3[col * 2 + 1] - W3[col * 2 + 0];
    }
    const float b3d = b3[1] - b3[0];

    const int j = lane >> 1, q = lane & 1;   // gather: 2 lanes per row
    const int G = gridDim.x;
    const int nTiles = (nRows + RPB - 1) / RPB;

    // esid for this lane's gather row of the first tile
    int e0, e1, e2;
    {
        int R = min(blockIdx.x * RPB + w * TROWS + j, nRows - 1);
        int n = R / 3;
        e0 = esid[n * 3 + 0]; e1 = esid[n * 3 + 1]; e2 = esid[n * 3 + 2];
    }

    for (int tI = blockIdx.x; tI < nTiles; tI += G) {
        const int base = tI * RPB + w * TROWS;

        // ---- gather row j (edge half q), 32 VGPR live per batch ----
        int R = min(base + j, nRows - 1);
        int f = R - 3 * (R / 3);
        long ea = (((long)e0 * kg + e1) * kg + e2) * 64;
        long na = ((((long)((f == 0) ? max(e0 - 1, 0) : e0)) * kg
                  + ((f == 1) ? max(e1 - 1, 0) : e1)) * kg
                  + ((f == 2) ? max(e2 - 1, 0) : e2)) * 64;
        const float4* pe = (const float4*)(topo + ea) + q * 8;
        const float4* pn = (const float4*)(topo + na) + q * 8;

        float4 eb[8];
        #pragma unroll
        for (int m = 0; m < 8; ++m) eb[m] = pe[m];

        // preload esid for next tile while loads are in flight
        {
            int Rn = min((tI + G) * RPB + w * TROWS + j, nRows - 1);
            int nn = Rn / 3;
            e0 = esid[nn * 3 + 0]; e1 = esid[nn * 3 + 1]; e2 = esid[nn * 3 + 2];
        }

        #pragma unroll
        for (int m = 0; m < 4; ++m)
            store8(tile, j, q * 32 + m * 8, eb[2 * m], eb[2 * m + 1]);

        float4 vb[8];
        #pragma unroll
        for (int m = 0; m < 8; ++m) vb[m] = pn[m];
        #pragma unroll
        for (int m = 0; m < 4; ++m)
            store8(tile, j, 64 + q * 32 + m * 8, vb[2 * m], vb[2 * m + 1]);

        // ---- layer-1 A fragments: lane holds row c31, k-chunk h*8 of each k-step ----
        s16x8 a[8];
        #pragma unroll
        for (int ks = 0; ks < 8; ++ks)
            a[ks] = *(const s16x8*)(tile + swz(c31, ks * 16 + h * 8));

        // ---- layer 1: per-n-tile MFMA + eager epilogue (X tile dead, reuse for H1) ----
        #pragma unroll
        for (int n = 0; n < 4; ++n) {
            f32x16 c = {0.f,0.f,0.f,0.f,0.f,0.f,0.f,0.f,0.f,0.f,0.f,0.f,0.f,0.f,0.f,0.f};
            #pragma unroll
            for (int ks = 0; ks < 8; ++ks) {
                s16x8 bf = *(const s16x8*)(sW1 + swz(n * 32 + c31, ks * 16 + h * 8));
                c = __builtin_amdgcn_mfma_f32_32x32x16_bf16(a[ks], bf, c, 0, 0, 0);
            }
            int col = n * 32 + c31;
            #pragma unroll
            for (int rg = 0; rg < 8; ++rg) {   // reg pairs (2rg, 2rg+1) -> rows r0, r0+1
                float h0 = fmaxf(c[2 * rg + 0] + rb1[n], 0.f);
                float h1 = fmaxf(c[2 * rg + 1] + rb1[n], 0.f);
                unsigned pk = cvt_pk(h0, h1);
                int r0 = ((2 * rg) & 3) + 8 * ((2 * rg) >> 2) + 4 * h;
                tile[swz(r0 + 0, col)] = (short)pk;
                tile[swz(r0 + 1, col)] = (short)(pk >> 16);
            }
        }

        // ---- layer 2 A fragments from H1 ----
        #pragma unroll
        for (int ks = 0; ks < 8; ++ks)
            a[ks] = *(const s16x8*)(tile + swz(c31, ks * 16 + h * 8));

        // ---- layer 2 MFMA + fused layer-3 logit-diff partials ----
        float pd[16];
        #pragma unroll
        for (int i = 0; i < 16; ++i) pd[i] = 0.f;
        #pragma unroll
        for (int n = 0; n < 4; ++n) {
            f32x16 c = {0.f,0.f,0.f,0.f,0.f,0.f,0.f,0.f,0.f,0.f,0.f,0.f,0.f,0.f,0.f,0.f};
            #pragma unroll
            for (int ks = 0; ks < 8; ++ks) {
                s16x8 bf = *(const s16x8*)(sW2 + swz(n * 32 + c31, ks * 16 + h * 8));
                c = __builtin_amdgcn_mfma_f32_32x32x16_bf16(a[ks], bf, c, 0, 0, 0);
            }
            #pragma unroll
            for (int reg = 0; reg < 16; ++reg) {
                float hh = fmaxf(c[reg] + rb2[n], 0.f);
                pd[reg] = fmaf(hh, w3d[n], pd[reg]);
            }
        }

        // ---- reduce each row's logit-diff over its 32 cols; select own value ----
        float dsel = 0.f;
        #pragma unroll
        for (int reg = 0; reg < 16; ++reg) {
            float v = red16(pd[reg]);
            v += __int_as_float(__builtin_amdgcn_ds_swizzle(__float_as_int(v), 0x401F));
            if ((c31 >> 1) == reg) dsel = v;
        }

        // ---- softmax + store: lane -> (row, o); 64 lanes = 32 rows x 2 outs ----
        {
            int o  = c31 & 1;
            int rg = c31 >> 1;
            int row = (rg & 3) + 8 * (rg >> 2) + 4 * h;
            float d = dsel + b3d;
            float p = 1.f / (1.f + __expf(o ? -d : d));
            int Ro = base + row;
            if (Ro < nRows) {
                int n = Ro / 3, ff = Ro - 3 * n;
                out[n * 6 + o * 3 + ff] = p;   // (N, 2, 3)
            }
        }
    }
}

extern "C" void kernel_launch(void* const* d_in, const int* in_sizes, int n_in,
                              void* d_out, int out_size, void* d_ws, size_t ws_size,
                              hipStream_t stream) {
    const float* topo = (const float*)d_in[0];
    const int*   esid = (const int*)d_in[1];
    const float* W1 = (const float*)d_in[2];
    const float* b1 = (const float*)d_in[3];
    const float* W2 = (const float*)d_in[4];
    const float* b2 = (const float*)d_in[5];
    const float* W3 = (const float*)d_in[6];
    const float* b3 = (const float*)d_in[7];
    float* out = (float*)d_out;

    int nRows = in_sizes[1];
    int H = in_sizes[3];
    int F = (in_sizes[2] / H) / 2;
    long vol = (long)in_sizes[0] / F;
    int kg = 1;
    while ((long)(kg + 1) * (kg + 1) * (kg + 1) <= vol) ++kg;

    if (nRows <= 0) return;
    edgeface_kernel<<<dim3(256), dim3(THREADS), 0, stream>>>(
        topo, esid, W1, b1, W2, b2, W3, b3, out, nRows, kg);
}

// Round 7
// 63.336 us; speedup vs baseline: 2.3586x; 1.3796x over previous
//
#include <hip/hip_runtime.h>

typedef __attribute__((ext_vector_type(8))) short s16x8;
typedef __attribute__((ext_vector_type(16))) float f32x16;

#define THREADS 512
#define WAVES 8
#define TROWS 32
#define RPB (WAVES * TROWS)   // 256 rows per block-tile

__device__ __forceinline__ short f2bf(float f) {
    unsigned u = __float_as_uint(f);
    u += 0x7fffu + ((u >> 16) & 1u);
    return (short)(u >> 16);
}

__device__ __forceinline__ unsigned cvt_pk(float lo, float hi) {
    unsigned r;
    asm("v_cvt_pk_bf16_f32 %0, %1, %2" : "=v"(r) : "v"(lo), "v"(hi));
    return r;
}

// swizzled ushort index into a [rows][128] bf16 tile; 16-granule XOR period
__device__ __forceinline__ int swz(int row, int col) {
    return row * 128 + ((((col >> 3) ^ (row & 15)) << 3) | (col & 7));
}

template <int S>
__device__ __forceinline__ float dpp_ror(float v) {
    int x = __builtin_amdgcn_update_dpp(0, __float_as_int(v), 0x120 | S, 0xf, 0xf, false);
    return __int_as_float(x);
}

__device__ __forceinline__ float red16(float v) {
    v += dpp_ror<1>(v);
    v += dpp_ror<2>(v);
    v += dpp_ror<4>(v);
    v += dpp_ror<8>(v);
    return v;
}

// pack 8 f32 -> bf16x8 A-fragment
__device__ __forceinline__ s16x8 pack8(float4 a, float4 b) {
    union { unsigned u[4]; s16x8 v; } z;
    z.u[0] = cvt_pk(a.x, a.y); z.u[1] = cvt_pk(a.z, a.w);
    z.u[2] = cvt_pk(b.x, b.y); z.u[3] = cvt_pk(b.z, b.w);
    return z.v;
}

__launch_bounds__(THREADS, 2)
__global__ void edgeface_kernel(
    const float* __restrict__ topo, const int* __restrict__ esid,
    const float* __restrict__ W1, const float* __restrict__ b1,
    const float* __restrict__ W2, const float* __restrict__ b2,
    const float* __restrict__ W3, const float* __restrict__ b3,
    float* __restrict__ out, int nRows, int kg)
{
    __shared__ __align__(16) short sW1[128 * 128];          // 32 KB, Wt[n][k]
    __shared__ __align__(16) short sW2[128 * 128];          // 32 KB
    __shared__ __align__(16) short sT[WAVES * TROWS * 128]; // 64 KB H1 per wave

    const int tid = threadIdx.x;

    for (int idx = tid; idx < 128 * 128; idx += THREADS) {
        int kk = idx >> 7, n = idx & 127;
        int d = swz(n, kk);
        sW1[d] = f2bf(W1[idx]);
        sW2[d] = f2bf(W2[idx]);
    }
    __syncthreads();

    const int w = tid >> 6, lane = tid & 63;
    short* tile = sT + w * (TROWS * 128);
    const int c31 = lane & 31;   // A-row (= this lane's gather row) / C-col
    const int h   = lane >> 5;   // k-half / C-row offset

    float rb1[4], rb2[4], w3d[4];
    #pragma unroll
    for (int n = 0; n < 4; ++n) {
        int col = n * 32 + c31;
        rb1[n] = b1[col];
        rb2[n] = b2[col];
        w3d[n] = W3[col * 2 + 1] - W3[col * 2 + 0];
    }
    const float b3d = b3[1] - b3[0];

    const int G = gridDim.x;
    const int nTiles = (nRows + RPB - 1) / RPB;

    // esid for this lane's row of the first tile
    int e0, e1, e2;
    {
        int R = min(blockIdx.x * RPB + w * TROWS + c31, nRows - 1);
        int n = R / 3;
        e0 = esid[n * 3 + 0]; e1 = esid[n * 3 + 1]; e2 = esid[n * 3 + 2];
    }

    // ---- prologue: issue gather for first tile (direct to A-fragment sources) ----
    float4 pf[16];
    {
        int R = min(blockIdx.x * RPB + w * TROWS + c31, nRows - 1);
        int f = R - 3 * (R / 3);
        long ea = (((long)e0 * kg + e1) * kg + e2) * 64;
        long na = ((((long)((f == 0) ? max(e0 - 1, 0) : e0)) * kg
                  + ((f == 1) ? max(e1 - 1, 0) : e1)) * kg
                  + ((f == 2) ? max(e2 - 1, 0) : e2)) * 64;
        const float4* pe = (const float4*)(topo + ea);
        const float4* pn = (const float4*)(topo + na);
        #pragma unroll
        for (int ks = 0; ks < 4; ++ks) {
            pf[2 * ks + 0] = pe[ks * 4 + h * 2 + 0];
            pf[2 * ks + 1] = pe[ks * 4 + h * 2 + 1];
            pf[8 + 2 * ks + 0] = pn[ks * 4 + h * 2 + 0];
            pf[8 + 2 * ks + 1] = pn[ks * 4 + h * 2 + 1];
        }
        // preload esid for next tile while loads fly
        int Rn = min((blockIdx.x + G) * RPB + w * TROWS + c31, nRows - 1);
        int nn = Rn / 3;
        e0 = esid[nn * 3 + 0]; e1 = esid[nn * 3 + 1]; e2 = esid[nn * 3 + 2];
    }

    for (int tI = blockIdx.x; tI < nTiles; tI += G) {
        const int base = tI * RPB + w * TROWS;

        // 1. pack current A-fragments (single consumption point; raw floats die here)
        s16x8 a[8];
        #pragma unroll
        for (int ks = 0; ks < 4; ++ks) {
            a[ks]     = pack8(pf[2 * ks], pf[2 * ks + 1]);
            a[4 + ks] = pack8(pf[8 + 2 * ks], pf[8 + 2 * ks + 1]);
        }

        // 2. issue next iteration's gather (esid already resident)
        {
            int Rn = min((tI + G) * RPB + w * TROWS + c31, nRows - 1);
            int f = Rn - 3 * (Rn / 3);
            long ea = (((long)e0 * kg + e1) * kg + e2) * 64;
            long na = ((((long)((f == 0) ? max(e0 - 1, 0) : e0)) * kg
                      + ((f == 1) ? max(e1 - 1, 0) : e1)) * kg
                      + ((f == 2) ? max(e2 - 1, 0) : e2)) * 64;
            const float4* pe = (const float4*)(topo + ea);
            const float4* pn = (const float4*)(topo + na);
            #pragma unroll
            for (int ks = 0; ks < 4; ++ks) {
                pf[2 * ks + 0] = pe[ks * 4 + h * 2 + 0];
                pf[2 * ks + 1] = pe[ks * 4 + h * 2 + 1];
                pf[8 + 2 * ks + 0] = pn[ks * 4 + h * 2 + 0];
                pf[8 + 2 * ks + 1] = pn[ks * 4 + h * 2 + 1];
            }
        }
        // 3. preload esid for tile tI+2G
        {
            int Rn = min((tI + 2 * G) * RPB + w * TROWS + c31, nRows - 1);
            int nn = Rn / 3;
            e0 = esid[nn * 3 + 0]; e1 = esid[nn * 3 + 1]; e2 = esid[nn * 3 + 2];
        }

        // 4. layer 1: per-n-tile MFMA + eager epilogue -> H1 in LDS
        #pragma unroll
        for (int n = 0; n < 4; ++n) {
            f32x16 c = {0.f,0.f,0.f,0.f,0.f,0.f,0.f,0.f,0.f,0.f,0.f,0.f,0.f,0.f,0.f,0.f};
            #pragma unroll
            for (int ks = 0; ks < 8; ++ks) {
                s16x8 bf = *(const s16x8*)(sW1 + swz(n * 32 + c31, ks * 16 + h * 8));
                c = __builtin_amdgcn_mfma_f32_32x32x16_bf16(a[ks], bf, c, 0, 0, 0);
            }
            int col = n * 32 + c31;
            #pragma unroll
            for (int rg = 0; rg < 8; ++rg) {
                float h0 = fmaxf(c[2 * rg + 0] + rb1[n], 0.f);
                float h1 = fmaxf(c[2 * rg + 1] + rb1[n], 0.f);
                unsigned pk = cvt_pk(h0, h1);
                int r0 = ((2 * rg) & 3) + 8 * ((2 * rg) >> 2) + 4 * h;
                tile[swz(r0 + 0, col)] = (short)pk;
                tile[swz(r0 + 1, col)] = (short)(pk >> 16);
            }
        }

        // 5. layer 2 A fragments from H1
        #pragma unroll
        for (int ks = 0; ks < 8; ++ks)
            a[ks] = *(const s16x8*)(tile + swz(c31, ks * 16 + h * 8));

        // layer 2 MFMA + fused layer-3 logit-diff partials
        float pd[16];
        #pragma unroll
        for (int i = 0; i < 16; ++i) pd[i] = 0.f;
        #pragma unroll
        for (int n = 0; n < 4; ++n) {
            f32x16 c = {0.f,0.f,0.f,0.f,0.f,0.f,0.f,0.f,0.f,0.f,0.f,0.f,0.f,0.f,0.f,0.f};
            #pragma unroll
            for (int ks = 0; ks < 8; ++ks) {
                s16x8 bf = *(const s16x8*)(sW2 + swz(n * 32 + c31, ks * 16 + h * 8));
                c = __builtin_amdgcn_mfma_f32_32x32x16_bf16(a[ks], bf, c, 0, 0, 0);
            }
            #pragma unroll
            for (int reg = 0; reg < 16; ++reg) {
                float hh = fmaxf(c[reg] + rb2[n], 0.f);
                pd[reg] = fmaf(hh, w3d[n], pd[reg]);
            }
        }

        // reduce each row's logit-diff over its 32 cols; select own value
        float dsel = 0.f;
        #pragma unroll
        for (int reg = 0; reg < 16; ++reg) {
            float v = red16(pd[reg]);
            v += __int_as_float(__builtin_amdgcn_ds_swizzle(__float_as_int(v), 0x401F));
            if ((c31 >> 1) == reg) dsel = v;
        }

        // softmax + store: 64 lanes = 32 rows x 2 outputs
        {
            int o  = c31 & 1;
            int rg = c31 >> 1;
            int row = (rg & 3) + 8 * (rg >> 2) + 4 * h;
            float d = dsel + b3d;
            float p = 1.f / (1.f + __expf(o ? -d : d));
            int Ro = base + row;
            if (Ro < nRows) {
                int n = Ro / 3, ff = Ro - 3 * n;
                out[n * 6 + o * 3 + ff] = p;   // (N, 2, 3)
            }
        }
    }
}

extern "C" void kernel_launch(void* const* d_in, const int* in_sizes, int n_in,
                              void* d_out, int out_size, void* d_ws, size_t ws_size,
                              hipStream_t stream) {
    const float* topo = (const float*)d_in[0];
    const int*   esid = (const int*)d_in[1];
    const float* W1 = (const float*)d_in[2];
    const float* b1 = (const float*)d_in[3];
    const float* W2 = (const float*)d_in[4];
    const float* b2 = (const float*)d_in[5];
    const float* W3 = (const float*)d_in[6];
    const float* b3 = (const float*)d_in[7];
    float* out = (float*)d_out;

    int nRows = in_sizes[1];
    int H = in_sizes[3];
    int F = (in_sizes[2] / H) / 2;
    long vol = (long)in_sizes[0] / F;
    int kg = 1;
    while ((long)(kg + 1) * (kg + 1) * (kg + 1) <= vol) ++kg;

    if (nRows <= 0) return;
    edgeface_kernel<<<dim3(256), dim3(THREADS), 0, stream>>>(
        topo, esid, W1, b1, W2, b2, W3, b3, out, nRows, kg);
}